// Round 3
// 1077.225 us; speedup vs baseline: 1.4353x; 1.4353x over previous
//
#include <hip/hip_runtime.h>
#include <math.h>

namespace {

constexpr int Hn = 50;    // hidden size
constexpr int Bn = 2048;  // batch
constexpr int Tn = 512;   // sequence length
constexpr int SW = 72;    // plane row stride in shorts (144 B: 16B-slot stride 16 mod 128 -> 2-way = free)

constexpr float KS1f = -1.44269504088896340736f;  // -log2(e)   (sigmoid rows i,f,o)
constexpr float KS2f = -2.88539008177792681472f;  // -2*log2(e) (tanh row g, and tanh(c))

typedef short short8 __attribute__((ext_vector_type(8)));
typedef float f32x4 __attribute__((ext_vector_type(4)));

__device__ __forceinline__ unsigned bcu(float f) { return __builtin_bit_cast(unsigned, f); }
__device__ __forceinline__ float bcf(unsigned u) { return __builtin_bit_cast(float, u); }
__device__ __forceinline__ float rcpa(float x) { return __builtin_amdgcn_rcpf(x); }

// 2^x. Guarded: __builtin_amdgcn_exp2f is the direct v_exp_f32 path; if this
// toolchain doesn't have it, exp2f() (OCML) lowers to v_exp_f32 + fixups.
__device__ __forceinline__ float fexp2(float x) {
#if defined(__has_builtin)
#if __has_builtin(__builtin_amdgcn_exp2f)
  return __builtin_amdgcn_exp2f(x);
#else
  return exp2f(x);
#endif
#else
  return exp2f(x);
#endif
}

__device__ __forceinline__ void wsplit(short* ph, short* pl, float v) {
  const unsigned u = bcu(v);
  *ph = (short)(u >> 16);
  *pl = (short)(bcu(v - bcf(u & 0xFFFF0000u)) >> 16);
}

#define MF(a, b, c) __builtin_amdgcn_mfma_f32_16x16x32_bf16(a, b, c, 0, 0, 0)

// ============================================================================
// FUSED 3-layer LSTM + FC, systolic in time. 128 blocks x 512 thr (8 waves =
// l1:2, l2:3, l3:3), 16 elems/block, ONE barrier/iter.
// R9/R10 changes (kill the scratch spills -- the real stall, not VALU):
//  - __launch_bounds__(512, 1): VGPR cap 128 -> 256. R8's cap of 128 forced
//    ~110 VGPRs/thread of weight fragments into scratch (WRITE_SIZE was
//    9992 KB = one-time spill stores; reloads every iter from L2/L3 = the
//    ~5000 stall cycles/timestep behind MfmaUtil 11% / VALUBusy 17%).
//  - bias vectors moved to LDS (broadcast ds_read_b128 per tile per iter):
//    -20..28 VGPRs of safety margin under the 256 cap.
//  - exp2-prescaled weights/biases: sigmoid rows scaled by -log2e, tanh(g)
//    rows by -2log2e, so gates are rcp(1+exp2(z')) with zero per-element
//    range-reduction muls. tanh via 2*rcp(1+e)-1 (no abs/copysign).
//  - R10: fexp2 guarded by __has_builtin (compile-proof on any ROCm).
// fp32 accuracy via 3-term split-bf16 (Wh*Uh + Wl*Uh + Wh*Ul); weight frags =
// MFMA operands (reg-resident); planes all K=64: P1=[x,h1(1..50)], P2=[h2],
// P3=[h3]; l2 consumes {P1,P2}, l3 consumes {P2,P3} with combined k-mapping.
// ============================================================================

#define LW(FI)                                                               \
  short8 FH##FI = {0, 0, 0, 0, 0, 0, 0, 0};                                  \
  short8 FL##FI = {0, 0, 0, 0, 0, 0, 0, 0};                                  \
  {                                                                          \
    const int tile_ = (L == 0) ? (wl + 2 * ((FI) >> 1))                      \
                               : (wl + 3 * ((FI) >> 2));                     \
    const int chunk_ = (L == 0) ? ((FI)&1) : ((FI)&3);                       \
    const int cb_ = 4 * tile_ + (nl >> 2);                                   \
    if (tile_ < 13 && cb_ < Hn) {                                            \
      const int row_ = (nl & 3) * Hn + cb_;                                  \
      const float sc_ = ((nl & 3) == 2) ? KS2f : KS1f;                       \
      _Pragma("unroll") for (int jj = 0; jj < 8; ++jj) {                     \
        const int k_ = 32 * chunk_ + quad * 8 + jj;                          \
        float wv = 0.f;                                                      \
        if (L == 0) {                                                        \
          if (k_ == 0) wv = wihL[row_];                                      \
          else if (k_ <= Hn) wv = whhL[row_ * Hn + k_ - 1];                  \
        } else if (L == 1) {                                                 \
          if (k_ >= 1 && k_ <= Hn) wv = wihL[row_ * Hn + k_ - 1];            \
          else if (k_ >= 64 && k_ < 64 + Hn) wv = whhL[row_ * Hn + k_ - 64]; \
        } else {                                                             \
          if (k_ < Hn) wv = wihL[row_ * Hn + k_];                            \
          else if (k_ >= 64 && k_ < 64 + Hn) wv = whhL[row_ * Hn + k_ - 64]; \
        }                                                                    \
        wv *= sc_;                                                           \
        const unsigned uu = bcu(wv);                                         \
        FH##FI[jj] = (short)(uu >> 16);                                      \
        FL##FI[jj] = (short)(bcu(wv - bcf(uu & 0xFFFF0000u)) >> 16);         \
      }                                                                      \
    }                                                                        \
  }

#define BINIT(J)                                                             \
  const int tile##J =                                                        \
      (L == 0) ? (wl + 2 * (J)) : ((J) < 5 ? (wl + 3 * (J)) : 13);           \
  const int tv##J = tile##J < 13;                                            \
  const int cell##J = 4 * tile##J + quad;                                    \
  float cs##J = 0.f, hl##J = 0.f;

// one-time prologue store of pre-scaled bias into LDS (nl==0 lanes only)
#define STB(J)                                                               \
  if (tv##J) {                                                               \
    float b0_ = 0.f, b1_ = 0.f, b2_ = 0.f, b3_ = 0.f;                        \
    if (cell##J < Hn) {                                                      \
      b0_ = biasL[cell##J] * KS1f;                                           \
      b1_ = biasL[Hn + cell##J] * KS1f;                                      \
      b2_ = biasL[2 * Hn + cell##J] * KS2f;                                  \
      b3_ = biasL[3 * Hn + cell##J] * KS1f;                                  \
    }                                                                        \
    s_bv[w][J][quad][0] = b0_;                                               \
    s_bv[w][J][quad][1] = b1_;                                               \
    s_bv[w][J][quad][2] = b2_;                                               \
    s_bv[w][J][quad][3] = b3_;                                               \
  }

#define MTM(J, FI)                                                           \
  if (tv##J) {                                                               \
    ac##J = MF(FH##FI, uh_, ac##J);                                          \
    ac##J = MF(FL##FI, uh_, ac##J);                                          \
    ac##J = MF(FH##FI, ul_, ac##J);                                          \
  }

// LC = chunk offset within the source plane (0 or 1)
#define MCH5(PH, PL, LC, F0, F1, F2, F3, F4)                                 \
  {                                                                          \
    const short8 uh_ = *(const short8*)&PH[rb][nl][32 * (LC) + quad * 8];    \
    const short8 ul_ = *(const short8*)&PL[rb][nl][32 * (LC) + quad * 8];    \
    MTM(0, F0) MTM(1, F1) MTM(2, F2) MTM(3, F3) MTM(4, F4)                   \
  }

#define MCH7(LC, F0, F1, F2, F3, F4, F5, F6)                                 \
  {                                                                          \
    const short8 uh_ = *(const short8*)&p1h[rb][nl][32 * (LC) + quad * 8];   \
    const short8 ul_ = *(const short8*)&p1l[rb][nl][32 * (LC) + quad * 8];   \
    MTM(0, F0) MTM(1, F1) MTM(2, F2) MTM(3, F3) MTM(4, F4) MTM(5, F5)        \
    MTM(6, F6)                                                               \
  }

// cell update for tile J; SINGLE h write into plane (PH,PL) at k = KO+cell
// gates arrive pre-scaled: sigmoid = rcp(1+exp2(z')), tanh = 2*rcp(1+e)-1
#define CUP(J, PH, PL, KO)                                                   \
  if (tv##J) {                                                               \
    const float I_ = rcpa(1.0f + fexp2(ac##J[0]));                           \
    const float F_ = rcpa(1.0f + fexp2(ac##J[1]));                           \
    const float G_ = fmaf(2.0f, rcpa(1.0f + fexp2(ac##J[2])), -1.0f);        \
    const float O_ = rcpa(1.0f + fexp2(ac##J[3]));                           \
    cs##J = fmaf(F_, cs##J, I_ * G_);                                        \
    const float tc_ = fmaf(2.0f, rcpa(1.0f + fexp2(cs##J * KS2f)), -1.0f);   \
    const float hv = O_ * tc_;                                               \
    hl##J = hv;                                                              \
    if (cell##J < Hn)                                                        \
      wsplit(&PH[wb][nl][(KO) + cell##J], &PL[wb][nl][(KO) + cell##J], hv);  \
  }

__global__ __launch_bounds__(512, 1) void lstm_fused(
    const float* __restrict__ xg,    // [B][T]
    const float* __restrict__ wih1, const float* __restrict__ whh1,
    const float* __restrict__ b1, const float* __restrict__ wih2,
    const float* __restrict__ whh2, const float* __restrict__ b2,
    const float* __restrict__ wih3, const float* __restrict__ whh3,
    const float* __restrict__ b3, const float* __restrict__ wfc,
    const float* __restrict__ bfc, float* __restrict__ out)  // [B]
{
  __shared__ __align__(16) short p1h[2][16][SW];  // [x | h1(1..50)]
  __shared__ __align__(16) short p1l[2][16][SW];
  __shared__ __align__(16) short p2h[2][16][SW];  // [h2(0..49)]
  __shared__ __align__(16) short p2l[2][16][SW];
  __shared__ __align__(16) short p3h[2][16][SW];  // [h3(0..49)]
  __shared__ __align__(16) short p3l[2][16][SW];
  __shared__ __align__(16) float s_bv[8][7][4][4];  // pre-scaled bias / wave,tile,quad
  __shared__ float s_fc[3][16];

  const int tid = threadIdx.x;
  const int w = tid >> 6;
  const int lane = tid & 63;
  const int quad = lane >> 4;
  const int nl = lane & 15;
  const int L = (w < 2) ? 0 : (w < 5) ? 1 : 2;
  const int wl = w - (L == 0 ? 0 : (L == 1 ? 2 : 5));
  const int eb = blockIdx.x * 16;

  const float* wihL = (L == 0) ? wih1 : (L == 1) ? wih2 : wih3;
  const float* whhL = (L == 0) ? whh1 : (L == 1) ? whh2 : whh3;
  const float* biasL = (L == 0) ? b1 : (L == 1) ? b2 : b3;

  LW(0) LW(1) LW(2) LW(3) LW(4) LW(5) LW(6) LW(7) LW(8) LW(9)
  LW(10) LW(11) LW(12) LW(13) LW(14) LW(15) LW(16) LW(17) LW(18) LW(19)

  BINIT(0) BINIT(1) BINIT(2) BINIT(3) BINIT(4) BINIT(5) BINIT(6)

  for (int i = tid; i < 2 * 16 * SW; i += 512) {
    (&p1h[0][0][0])[i] = 0;
    (&p1l[0][0][0])[i] = 0;
    (&p2h[0][0][0])[i] = 0;
    (&p2l[0][0][0])[i] = 0;
    (&p3h[0][0][0])[i] = 0;
    (&p3l[0][0][0])[i] = 0;
  }
  for (int i = tid; i < 8 * 7 * 4 * 4; i += 512) (&s_bv[0][0][0][0])[i] = 0.f;
  __syncthreads();
  if (w == 0 && lane < 16) {
    const float xv = xg[(size_t)(eb + lane) * Tn + 0];
    wsplit(&p1h[0][lane][0], &p1l[0][lane][0], xv);
  }
  if (nl == 0) {
    STB(0) STB(1) STB(2) STB(3) STB(4) STB(5) STB(6)
  }
  __syncthreads();

#pragma unroll 1
  for (int i = 0; i < Tn + 2; ++i) {
    const int rb = i & 1, wb = rb ^ 1;
    if (L == 0) {
      if (i < Tn) {
        float xv = 0.f;
        if (w == 0 && lane < 16 && i + 1 < Tn)
          xv = xg[(size_t)(eb + lane) * Tn + (i + 1)];
        f32x4 ac0 = *(const f32x4*)s_bv[w][0][quad];
        f32x4 ac1 = *(const f32x4*)s_bv[w][1][quad];
        f32x4 ac2 = *(const f32x4*)s_bv[w][2][quad];
        f32x4 ac3 = *(const f32x4*)s_bv[w][3][quad];
        f32x4 ac4 = *(const f32x4*)s_bv[w][4][quad];
        f32x4 ac5 = *(const f32x4*)s_bv[w][5][quad];
        f32x4 ac6 = *(const f32x4*)s_bv[w][6][quad];
        MCH7(0, 0, 2, 4, 6, 8, 10, 12)
        MCH7(1, 1, 3, 5, 7, 9, 11, 13)
        CUP(0, p1h, p1l, 1)
        CUP(1, p1h, p1l, 1)
        CUP(2, p1h, p1l, 1)
        CUP(3, p1h, p1l, 1)
        CUP(4, p1h, p1l, 1)
        CUP(5, p1h, p1l, 1)
        CUP(6, p1h, p1l, 1)
        if (w == 0 && lane < 16)
          wsplit(&p1h[wb][lane][0], &p1l[wb][lane][0], xv);
      }
    } else if (L == 1) {
      if (i >= 1 && i <= Tn) {
        f32x4 ac0 = *(const f32x4*)s_bv[w][0][quad];
        f32x4 ac1 = *(const f32x4*)s_bv[w][1][quad];
        f32x4 ac2 = *(const f32x4*)s_bv[w][2][quad];
        f32x4 ac3 = *(const f32x4*)s_bv[w][3][quad];
        f32x4 ac4 = *(const f32x4*)s_bv[w][4][quad];
        MCH5(p1h, p1l, 0, 0, 4, 8, 12, 16)    // combined k 0..31  (h1)
        MCH5(p1h, p1l, 1, 1, 5, 9, 13, 17)    // combined k 32..63 (h1)
        MCH5(p2h, p2l, 0, 2, 6, 10, 14, 18)   // combined k 64..95 (h2)
        MCH5(p2h, p2l, 1, 3, 7, 11, 15, 19)   // combined k 96..127(h2)
        CUP(0, p2h, p2l, 0)
        CUP(1, p2h, p2l, 0)
        CUP(2, p2h, p2l, 0)
        CUP(3, p2h, p2l, 0)
        CUP(4, p2h, p2l, 0)
      }
    } else {
      if (i >= 2) {
        f32x4 ac0 = *(const f32x4*)s_bv[w][0][quad];
        f32x4 ac1 = *(const f32x4*)s_bv[w][1][quad];
        f32x4 ac2 = *(const f32x4*)s_bv[w][2][quad];
        f32x4 ac3 = *(const f32x4*)s_bv[w][3][quad];
        f32x4 ac4 = *(const f32x4*)s_bv[w][4][quad];
        MCH5(p2h, p2l, 0, 0, 4, 8, 12, 16)    // h2
        MCH5(p2h, p2l, 1, 1, 5, 9, 13, 17)
        MCH5(p3h, p3l, 0, 2, 6, 10, 14, 18)   // h3
        MCH5(p3h, p3l, 1, 3, 7, 11, 15, 19)
        CUP(0, p3h, p3l, 0)
        CUP(1, p3h, p3l, 0)
        CUP(2, p3h, p3l, 0)
        CUP(3, p3h, p3l, 0)
        CUP(4, p3h, p3l, 0)
      }
    }
    __syncthreads();
  }

  if (L == 2) {
    float pfc = 0.f;
    if (tv0 && cell0 < Hn) pfc += hl0 * wfc[cell0];
    if (tv1 && cell1 < Hn) pfc += hl1 * wfc[cell1];
    if (tv2 && cell2 < Hn) pfc += hl2 * wfc[cell2];
    if (tv3 && cell3 < Hn) pfc += hl3 * wfc[cell3];
    if (tv4 && cell4 < Hn) pfc += hl4 * wfc[cell4];
    pfc += __shfl_xor(pfc, 16);  // sum over quads (cells)
    pfc += __shfl_xor(pfc, 32);
    if (lane < 16) s_fc[wl][lane] = pfc;
  }
  __syncthreads();
  if (tid < 16)
    out[eb + tid] = bfc[0] + s_fc[0][tid] + s_fc[1][tid] + s_fc[2][tid];
}

}  // namespace

extern "C" void kernel_launch(void* const* d_in, const int* in_sizes, int n_in,
                              void* d_out, int out_size, void* d_ws, size_t ws_size,
                              hipStream_t stream) {
  const float* x    = (const float*)d_in[0];
  const float* wih1 = (const float*)d_in[1];
  const float* whh1 = (const float*)d_in[2];
  const float* b1   = (const float*)d_in[3];
  const float* wih2 = (const float*)d_in[4];
  const float* whh2 = (const float*)d_in[5];
  const float* b2   = (const float*)d_in[6];
  const float* wih3 = (const float*)d_in[7];
  const float* whh3 = (const float*)d_in[8];
  const float* b3   = (const float*)d_in[9];
  const float* wfc  = (const float*)d_in[10];
  const float* bfc  = (const float*)d_in[11];
  float* out = (float*)d_out;

  lstm_fused<<<dim3(Bn / 16), dim3(512), 0, stream>>>(
      x, wih1, whh1, b1, wih2, whh2, b2, wih3, whh3, b3, wfc, bfc, out);
}

// Round 4
// 971.389 us; speedup vs baseline: 1.5916x; 1.1090x over previous
//
#include <hip/hip_runtime.h>
#include <math.h>

namespace {

constexpr int Hn = 50;    // hidden size
constexpr int Bn = 2048;  // batch
constexpr int Tn = 512;   // sequence length
constexpr int SW = 72;    // plane row stride in shorts (144 B: 16B-slot stride 16 mod 128 -> 2-way = free)

constexpr float KS1f = -1.44269504088896340736f;  // -log2(e)   (sigmoid rows i,f,o)
constexpr float KS2f = -2.88539008177792681472f;  // -2*log2(e) (tanh row g, and tanh(c))

typedef short short8 __attribute__((ext_vector_type(8)));
typedef float f32x4 __attribute__((ext_vector_type(4)));

__device__ __forceinline__ unsigned bcu(float f) { return __builtin_bit_cast(unsigned, f); }
__device__ __forceinline__ float bcf(unsigned u) { return __builtin_bit_cast(float, u); }
__device__ __forceinline__ float rcpa(float x) { return __builtin_amdgcn_rcpf(x); }

// 2^x. Guarded: __builtin_amdgcn_exp2f is the direct v_exp_f32 path; if this
// toolchain doesn't have it, exp2f() (OCML) lowers to v_exp_f32 + fixups.
__device__ __forceinline__ float fexp2(float x) {
#if defined(__has_builtin)
#if __has_builtin(__builtin_amdgcn_exp2f)
  return __builtin_amdgcn_exp2f(x);
#else
  return exp2f(x);
#endif
#else
  return exp2f(x);
#endif
}

__device__ __forceinline__ void wsplit(short* ph, short* pl, float v) {
  const unsigned u = bcu(v);
  *ph = (short)(u >> 16);
  *pl = (short)(bcu(v - bcf(u & 0xFFFF0000u)) >> 16);
}

#define MF(a, b, c) __builtin_amdgcn_mfma_f32_16x16x32_bf16(a, b, c, 0, 0, 0)

// ============================================================================
// FUSED 3-layer LSTM + FC, systolic in time. 128 blocks x 512 thr (8 waves =
// l1:2, l2:3, l3:3), 16 elems/block, ONE barrier/iter.
// R11 change (finish killing the spills):
//  - 512-thr blocks structurally force >=2 waves/SIMD, so the unified
//    VGPR+AGPR cap is 256/wave regardless of __launch_bounds__. R10 demand
//    was ~270 -> ~13 dwords/thread still spilled (WRITE_SIZE 3336 KB),
//    reloaded from scratch every iteration = the remaining stall.
//  - Fix: tile J=4's weight fragments (FH16..19/FL16..19 = 64 VGPRs) move
//    to LDS (s_f4, 16 KB); only waves wl==0 of L1/L2 use tile 4, they read
//    them back per chunk via ds_read_b128 (MTMS). Bit-identical math.
//  - demand ~270 -> ~205 < 256 cap -> zero spills expected.
// R9/R10 (kept): __launch_bounds__(512,1); bias in LDS; exp2-prescaled
// weights/biases (sigmoid rows * -log2e, tanh rows * -2log2e) so gates are
// rcp(1+exp2(z')); tanh = 2*rcp(1+e)-1; guarded fexp2.
// fp32 accuracy via 3-term split-bf16 (Wh*Uh + Wl*Uh + Wh*Ul); planes K=64:
// P1=[x,h1(1..50)], P2=[h2], P3=[h3]; l2 consumes {P1,P2}, l3 {P2,P3}.
// ============================================================================

#define LW(FI)                                                               \
  short8 FH##FI = {0, 0, 0, 0, 0, 0, 0, 0};                                  \
  short8 FL##FI = {0, 0, 0, 0, 0, 0, 0, 0};                                  \
  {                                                                          \
    const int tile_ = (L == 0) ? (wl + 2 * ((FI) >> 1))                      \
                               : (wl + 3 * ((FI) >> 2));                     \
    const int chunk_ = (L == 0) ? ((FI)&1) : ((FI)&3);                       \
    const int cb_ = 4 * tile_ + (nl >> 2);                                   \
    if (tile_ < 13 && cb_ < Hn) {                                            \
      const int row_ = (nl & 3) * Hn + cb_;                                  \
      const float sc_ = ((nl & 3) == 2) ? KS2f : KS1f;                       \
      _Pragma("unroll") for (int jj = 0; jj < 8; ++jj) {                     \
        const int k_ = 32 * chunk_ + quad * 8 + jj;                          \
        float wv = 0.f;                                                      \
        if (L == 0) {                                                        \
          if (k_ == 0) wv = wihL[row_];                                      \
          else if (k_ <= Hn) wv = whhL[row_ * Hn + k_ - 1];                  \
        } else if (L == 1) {                                                 \
          if (k_ >= 1 && k_ <= Hn) wv = wihL[row_ * Hn + k_ - 1];            \
          else if (k_ >= 64 && k_ < 64 + Hn) wv = whhL[row_ * Hn + k_ - 64]; \
        } else {                                                             \
          if (k_ < Hn) wv = wihL[row_ * Hn + k_];                            \
          else if (k_ >= 64 && k_ < 64 + Hn) wv = whhL[row_ * Hn + k_ - 64]; \
        }                                                                    \
        wv *= sc_;                                                           \
        const unsigned uu = bcu(wv);                                         \
        FH##FI[jj] = (short)(uu >> 16);                                      \
        FL##FI[jj] = (short)(bcu(wv - bcf(uu & 0xFFFF0000u)) >> 16);         \
      }                                                                      \
    }                                                                        \
  }

#define BINIT(J)                                                             \
  const int tile##J =                                                        \
      (L == 0) ? (wl + 2 * (J)) : ((J) < 5 ? (wl + 3 * (J)) : 13);           \
  const int tv##J = tile##J < 13;                                            \
  const int cell##J = 4 * tile##J + quad;                                    \
  float cs##J = 0.f, hl##J = 0.f;

// one-time prologue store of pre-scaled bias into LDS (nl==0 lanes only)
#define STB(J)                                                               \
  if (tv##J) {                                                               \
    float b0_ = 0.f, b1_ = 0.f, b2_ = 0.f, b3_ = 0.f;                        \
    if (cell##J < Hn) {                                                      \
      b0_ = biasL[cell##J] * KS1f;                                           \
      b1_ = biasL[Hn + cell##J] * KS1f;                                      \
      b2_ = biasL[2 * Hn + cell##J] * KS2f;                                  \
      b3_ = biasL[3 * Hn + cell##J] * KS1f;                                  \
    }                                                                        \
    s_bv[w][J][quad][0] = b0_;                                               \
    s_bv[w][J][quad][1] = b1_;                                               \
    s_bv[w][J][quad][2] = b2_;                                               \
    s_bv[w][J][quad][3] = b3_;                                               \
  }

#define MTM(J, FI)                                                           \
  if (tv##J) {                                                               \
    ac##J = MF(FH##FI, uh_, ac##J);                                          \
    ac##J = MF(FL##FI, uh_, ac##J);                                          \
    ac##J = MF(FH##FI, ul_, ac##J);                                          \
  }

// tile J=4's fragments live in LDS (only waves wl==0 of L1/L2 have tv4)
#define MTMS(CI)                                                             \
  if (tv4) {                                                                 \
    const short8 fh_ = s_f4[wz2][CI][0][lane];                               \
    const short8 fl_ = s_f4[wz2][CI][1][lane];                               \
    ac4 = MF(fh_, uh_, ac4);                                                 \
    ac4 = MF(fl_, uh_, ac4);                                                 \
    ac4 = MF(fh_, ul_, ac4);                                                 \
  }

// LC = chunk offset within the source plane (0 or 1); CI = combined chunk idx
#define MCH5(PH, PL, LC, CI, F0, F1, F2, F3)                                 \
  {                                                                          \
    const short8 uh_ = *(const short8*)&PH[rb][nl][32 * (LC) + quad * 8];    \
    const short8 ul_ = *(const short8*)&PL[rb][nl][32 * (LC) + quad * 8];    \
    MTM(0, F0) MTM(1, F1) MTM(2, F2) MTM(3, F3) MTMS(CI)                     \
  }

#define MCH7(LC, F0, F1, F2, F3, F4, F5, F6)                                 \
  {                                                                          \
    const short8 uh_ = *(const short8*)&p1h[rb][nl][32 * (LC) + quad * 8];   \
    const short8 ul_ = *(const short8*)&p1l[rb][nl][32 * (LC) + quad * 8];   \
    MTM(0, F0) MTM(1, F1) MTM(2, F2) MTM(3, F3) MTM(4, F4) MTM(5, F5)        \
    MTM(6, F6)                                                               \
  }

// cell update for tile J; SINGLE h write into plane (PH,PL) at k = KO+cell
// gates arrive pre-scaled: sigmoid = rcp(1+exp2(z')), tanh = 2*rcp(1+e)-1
#define CUP(J, PH, PL, KO)                                                   \
  if (tv##J) {                                                               \
    const float I_ = rcpa(1.0f + fexp2(ac##J[0]));                           \
    const float F_ = rcpa(1.0f + fexp2(ac##J[1]));                           \
    const float G_ = fmaf(2.0f, rcpa(1.0f + fexp2(ac##J[2])), -1.0f);        \
    const float O_ = rcpa(1.0f + fexp2(ac##J[3]));                           \
    cs##J = fmaf(F_, cs##J, I_ * G_);                                        \
    const float tc_ = fmaf(2.0f, rcpa(1.0f + fexp2(cs##J * KS2f)), -1.0f);   \
    const float hv = O_ * tc_;                                               \
    hl##J = hv;                                                              \
    if (cell##J < Hn)                                                        \
      wsplit(&PH[wb][nl][(KO) + cell##J], &PL[wb][nl][(KO) + cell##J], hv);  \
  }

__global__ __launch_bounds__(512, 1) void lstm_fused(
    const float* __restrict__ xg,    // [B][T]
    const float* __restrict__ wih1, const float* __restrict__ whh1,
    const float* __restrict__ b1, const float* __restrict__ wih2,
    const float* __restrict__ whh2, const float* __restrict__ b2,
    const float* __restrict__ wih3, const float* __restrict__ whh3,
    const float* __restrict__ b3, const float* __restrict__ wfc,
    const float* __restrict__ bfc, float* __restrict__ out)  // [B]
{
  __shared__ __align__(16) short p1h[2][16][SW];  // [x | h1(1..50)]
  __shared__ __align__(16) short p1l[2][16][SW];
  __shared__ __align__(16) short p2h[2][16][SW];  // [h2(0..49)]
  __shared__ __align__(16) short p2l[2][16][SW];
  __shared__ __align__(16) short p3h[2][16][SW];  // [h3(0..49)]
  __shared__ __align__(16) short p3l[2][16][SW];
  __shared__ __align__(16) float s_bv[8][7][4][4];  // pre-scaled bias / wave,tile,quad
  __shared__ __align__(16) short8 s_f4[2][4][2][64];  // tile-4 frags: [L-1][chunk][H/L][lane]
  __shared__ float s_fc[3][16];

  const int tid = threadIdx.x;
  const int w = tid >> 6;
  const int lane = tid & 63;
  const int quad = lane >> 4;
  const int nl = lane & 15;
  const int L = (w < 2) ? 0 : (w < 5) ? 1 : 2;
  const int wl = w - (L == 0 ? 0 : (L == 1 ? 2 : 5));
  const int wz2 = (L == 2) ? 1 : 0;
  const int eb = blockIdx.x * 16;

  const float* wihL = (L == 0) ? wih1 : (L == 1) ? wih2 : wih3;
  const float* whhL = (L == 0) ? whh1 : (L == 1) ? whh2 : whh3;
  const float* biasL = (L == 0) ? b1 : (L == 1) ? b2 : b3;

  LW(0) LW(1) LW(2) LW(3) LW(4) LW(5) LW(6) LW(7) LW(8) LW(9)
  LW(10) LW(11) LW(12) LW(13) LW(14) LW(15) LW(16) LW(17) LW(18) LW(19)

  // park tile-4 fragments in LDS; their registers die here (used by MTMS only)
  if (L > 0 && wl == 0) {
    s_f4[wz2][0][0][lane] = FH16; s_f4[wz2][0][1][lane] = FL16;
    s_f4[wz2][1][0][lane] = FH17; s_f4[wz2][1][1][lane] = FL17;
    s_f4[wz2][2][0][lane] = FH18; s_f4[wz2][2][1][lane] = FL18;
    s_f4[wz2][3][0][lane] = FH19; s_f4[wz2][3][1][lane] = FL19;
  }

  BINIT(0) BINIT(1) BINIT(2) BINIT(3) BINIT(4) BINIT(5) BINIT(6)

  for (int i = tid; i < 2 * 16 * SW; i += 512) {
    (&p1h[0][0][0])[i] = 0;
    (&p1l[0][0][0])[i] = 0;
    (&p2h[0][0][0])[i] = 0;
    (&p2l[0][0][0])[i] = 0;
    (&p3h[0][0][0])[i] = 0;
    (&p3l[0][0][0])[i] = 0;
  }
  for (int i = tid; i < 8 * 7 * 4 * 4; i += 512) (&s_bv[0][0][0][0])[i] = 0.f;
  __syncthreads();
  if (w == 0 && lane < 16) {
    const float xv = xg[(size_t)(eb + lane) * Tn + 0];
    wsplit(&p1h[0][lane][0], &p1l[0][lane][0], xv);
  }
  if (nl == 0) {
    STB(0) STB(1) STB(2) STB(3) STB(4) STB(5) STB(6)
  }
  __syncthreads();

#pragma unroll 1
  for (int i = 0; i < Tn + 2; ++i) {
    const int rb = i & 1, wb = rb ^ 1;
    if (L == 0) {
      if (i < Tn) {
        float xv = 0.f;
        if (w == 0 && lane < 16 && i + 1 < Tn)
          xv = xg[(size_t)(eb + lane) * Tn + (i + 1)];
        f32x4 ac0 = *(const f32x4*)s_bv[w][0][quad];
        f32x4 ac1 = *(const f32x4*)s_bv[w][1][quad];
        f32x4 ac2 = *(const f32x4*)s_bv[w][2][quad];
        f32x4 ac3 = *(const f32x4*)s_bv[w][3][quad];
        f32x4 ac4 = *(const f32x4*)s_bv[w][4][quad];
        f32x4 ac5 = *(const f32x4*)s_bv[w][5][quad];
        f32x4 ac6 = *(const f32x4*)s_bv[w][6][quad];
        MCH7(0, 0, 2, 4, 6, 8, 10, 12)
        MCH7(1, 1, 3, 5, 7, 9, 11, 13)
        CUP(0, p1h, p1l, 1)
        CUP(1, p1h, p1l, 1)
        CUP(2, p1h, p1l, 1)
        CUP(3, p1h, p1l, 1)
        CUP(4, p1h, p1l, 1)
        CUP(5, p1h, p1l, 1)
        CUP(6, p1h, p1l, 1)
        if (w == 0 && lane < 16)
          wsplit(&p1h[wb][lane][0], &p1l[wb][lane][0], xv);
      }
    } else if (L == 1) {
      if (i >= 1 && i <= Tn) {
        f32x4 ac0 = *(const f32x4*)s_bv[w][0][quad];
        f32x4 ac1 = *(const f32x4*)s_bv[w][1][quad];
        f32x4 ac2 = *(const f32x4*)s_bv[w][2][quad];
        f32x4 ac3 = *(const f32x4*)s_bv[w][3][quad];
        f32x4 ac4 = *(const f32x4*)s_bv[w][4][quad];
        MCH5(p1h, p1l, 0, 0, 0, 4, 8, 12)    // combined k 0..31  (h1)
        MCH5(p1h, p1l, 1, 1, 1, 5, 9, 13)    // combined k 32..63 (h1)
        MCH5(p2h, p2l, 0, 2, 2, 6, 10, 14)   // combined k 64..95 (h2)
        MCH5(p2h, p2l, 1, 3, 3, 7, 11, 15)   // combined k 96..127(h2)
        CUP(0, p2h, p2l, 0)
        CUP(1, p2h, p2l, 0)
        CUP(2, p2h, p2l, 0)
        CUP(3, p2h, p2l, 0)
        CUP(4, p2h, p2l, 0)
      }
    } else {
      if (i >= 2) {
        f32x4 ac0 = *(const f32x4*)s_bv[w][0][quad];
        f32x4 ac1 = *(const f32x4*)s_bv[w][1][quad];
        f32x4 ac2 = *(const f32x4*)s_bv[w][2][quad];
        f32x4 ac3 = *(const f32x4*)s_bv[w][3][quad];
        f32x4 ac4 = *(const f32x4*)s_bv[w][4][quad];
        MCH5(p2h, p2l, 0, 0, 0, 4, 8, 12)    // h2
        MCH5(p2h, p2l, 1, 1, 1, 5, 9, 13)
        MCH5(p3h, p3l, 0, 2, 2, 6, 10, 14)   // h3
        MCH5(p3h, p3l, 1, 3, 3, 7, 11, 15)
        CUP(0, p3h, p3l, 0)
        CUP(1, p3h, p3l, 0)
        CUP(2, p3h, p3l, 0)
        CUP(3, p3h, p3l, 0)
        CUP(4, p3h, p3l, 0)
      }
    }
    __syncthreads();
  }

  if (L == 2) {
    float pfc = 0.f;
    if (tv0 && cell0 < Hn) pfc += hl0 * wfc[cell0];
    if (tv1 && cell1 < Hn) pfc += hl1 * wfc[cell1];
    if (tv2 && cell2 < Hn) pfc += hl2 * wfc[cell2];
    if (tv3 && cell3 < Hn) pfc += hl3 * wfc[cell3];
    if (tv4 && cell4 < Hn) pfc += hl4 * wfc[cell4];
    pfc += __shfl_xor(pfc, 16);  // sum over quads (cells)
    pfc += __shfl_xor(pfc, 32);
    if (lane < 16) s_fc[wl][lane] = pfc;
  }
  __syncthreads();
  if (tid < 16)
    out[eb + tid] = bfc[0] + s_fc[0][tid] + s_fc[1][tid] + s_fc[2][tid];
}

}  // namespace

extern "C" void kernel_launch(void* const* d_in, const int* in_sizes, int n_in,
                              void* d_out, int out_size, void* d_ws, size_t ws_size,
                              hipStream_t stream) {
  const float* x    = (const float*)d_in[0];
  const float* wih1 = (const float*)d_in[1];
  const float* whh1 = (const float*)d_in[2];
  const float* b1   = (const float*)d_in[3];
  const float* wih2 = (const float*)d_in[4];
  const float* whh2 = (const float*)d_in[5];
  const float* b2   = (const float*)d_in[6];
  const float* wih3 = (const float*)d_in[7];
  const float* whh3 = (const float*)d_in[8];
  const float* b3   = (const float*)d_in[9];
  const float* wfc  = (const float*)d_in[10];
  const float* bfc  = (const float*)d_in[11];
  float* out = (float*)d_out;

  lstm_fused<<<dim3(Bn / 16), dim3(512), 0, stream>>>(
      x, wih1, whh1, b1, wih2, whh2, b2, wih3, whh3, b3, wfc, bfc, out);
}